// Round 3
// baseline (932.894 us; speedup 1.0000x reference)
//
#include <hip/hip_runtime.h>

// Problem constants (N=8192 rows, D=256 features)
#define NN 8192
#define DD 256
#define ND_ (NN * DD)

#define NEG_SLOPE 0.1f

// ---------------------------------------------------------------------------
// agg_kernel<SPLITK>: computes split-K partials of
//   P = (A + A^T) @ u      Q = (A^T - A) @ v      (u = h+d, v = h-d, on the fly)
// then per-element partials of
//   head_agg = 0.5*(P+Q) - diag*u     dep_agg = 0.5*(P-Q) - diag*u
// (diag term applied by the half==0 block only).
//
// Block tile: 64 rows x 128 cols, 256 threads.
//   waves 0-1 (t<128): P from (S, u);  waves 2-3: Q from (Dm, v).
//   Per thread: 8x8 f32 accumulator.
// Grid: 128 * 2 * SPLITK blocks.
// ---------------------------------------------------------------------------
template <int SPLITK>
__global__ __launch_bounds__(256, 2)
void agg_kernel(const float* __restrict__ alpha,
                const float* __restrict__ head,
                const float* __restrict__ dep,
                float* __restrict__ hA,    // [SPLITK][NN][DD] split-K partials
                float* __restrict__ dA) {  // [SPLITK][NN][DD]
    // LDS layout (floats):
    //  s_a1 [64][36]  : raw A[I, kblk] row-slab (padded for transpose read)
    //  s_S  [32][64]  : (A + A^T) tile, [k][r]
    //  s_Dm [32][64]  : (A^T - A) tile, [k][r]
    //  s_u  [32][128] : u tile  [k][c]
    //  s_v  [32][128] : v tile  [k][c]
    // Epilogue reuses smem[0..8192) as Pbuf, smem[8192..16384) as Qbuf.
    __shared__ float smem[16384];           // 64 KB
    float* s_a1 = smem;                     // 2304 floats
    float* s_S  = smem + 2304;              // 2048
    float* s_Dm = smem + 4352;              // 2048
    float* s_u  = smem + 6400;              // 4096
    float* s_v  = smem + 10496;             // 4096 -> 14592

    const int b = blockIdx.x;
    int half, cb, rb;
    if (SPLITK == 2) {
        half = b & 1;
        cb   = (b >> 1) & 1;
        rb   = b >> 2;
    } else {
        half = 0;
        cb   = b & 1;
        rb   = b >> 1;
    }
    const int I0 = rb * 64;
    const int C0 = cb * 128;
    const int t  = threadIdx.x;

    const bool isP = (t < 128);
    const int  tt  = t & 127;
    const int  r0  = (tt & 7) * 8;          // 8 row-groups
    const int  c0  = (tt >> 3) * 8;         // 16 col-groups

    const float* Ab = isP ? s_S : s_Dm;
    const float* Bb = isP ? s_u : s_v;

    float acc[8][8];
#pragma unroll
    for (int i = 0; i < 8; ++i)
#pragma unroll
        for (int j = 0; j < 8; ++j) acc[i][j] = 0.0f;

    const int kbase = half * (NN / SPLITK);
    const int iters = (NN / SPLITK) / 32;

    for (int it = 0; it < iters; ++it) {
        const int k0 = kbase + it * 32;
        __syncthreads();   // previous iter's LDS reads complete

        // ---- stage 1: global loads ----
        float4 a2r[2];
#pragma unroll
        for (int e = 0; e < 2; ++e) {
            int idx = e * 256 + t;
            int r   = idx >> 3;             // 0..63
            int k4  = (idx & 7) << 2;       // 0..28
            *(float4*)&s_a1[r * 36 + k4] =
                *(const float4*)&alpha[(I0 + r) * NN + k0 + k4];
            int kk = idx >> 4;              // 0..31
            int r4 = (idx & 15) << 2;       // 0..60
            a2r[e] = *(const float4*)&alpha[(k0 + kk) * NN + I0 + r4];
        }
#pragma unroll
        for (int e = 0; e < 4; ++e) {
            int idx = e * 256 + t;
            int kk  = idx >> 5;             // 0..31
            int c4  = (idx & 31) << 2;      // 0..124
            int go  = (k0 + kk) * DD + C0 + c4;
            float4 hv4 = *(const float4*)&head[go];
            float4 dv4 = *(const float4*)&dep[go];
            float4 uu, vv;
            uu.x = hv4.x + dv4.x; uu.y = hv4.y + dv4.y;
            uu.z = hv4.z + dv4.z; uu.w = hv4.w + dv4.w;
            vv.x = hv4.x - dv4.x; vv.y = hv4.y - dv4.y;
            vv.z = hv4.z - dv4.z; vv.w = hv4.w - dv4.w;
            *(float4*)&s_u[kk * 128 + c4] = uu;
            *(float4*)&s_v[kk * 128 + c4] = vv;
        }
        __syncthreads();   // s_a1 ready

        // ---- stage 2: build S = A^T+A and Dm = A^T-A tiles in [k][r] ----
#pragma unroll
        for (int e = 0; e < 2; ++e) {
            int idx = e * 256 + t;
            int kk  = idx >> 4;
            int r4  = (idx & 15) << 2;
            float4 a2 = a2r[e];             // a2.j = A[k0+kk][I0+r4+j]
            float t0 = s_a1[(r4 + 0) * 36 + kk];   // A[I0+r4+j][k0+kk]
            float t1 = s_a1[(r4 + 1) * 36 + kk];
            float t2 = s_a1[(r4 + 2) * 36 + kk];
            float t3 = s_a1[(r4 + 3) * 36 + kk];
            float4 sw, dw;
            sw.x = a2.x + t0; sw.y = a2.y + t1; sw.z = a2.z + t2; sw.w = a2.w + t3;
            dw.x = a2.x - t0; dw.y = a2.y - t1; dw.z = a2.z - t2; dw.w = a2.w - t3;
            *(float4*)&s_S [kk * 64 + r4] = sw;
            *(float4*)&s_Dm[kk * 64 + r4] = dw;
        }
        __syncthreads();   // S/Dm/u/v ready

        // ---- inner product: acc += op_tile[k][r] * vec_tile[k][c] ----
#pragma unroll 8
        for (int k = 0; k < 32; ++k) {
            float4 sa = *(const float4*)&Ab[k * 64 + r0];
            float4 sb = *(const float4*)&Ab[k * 64 + r0 + 4];
            float4 ua = *(const float4*)&Bb[k * 128 + c0];
            float4 ub = *(const float4*)&Bb[k * 128 + c0 + 4];
            float ss[8] = {sa.x, sa.y, sa.z, sa.w, sb.x, sb.y, sb.z, sb.w};
            float uu[8] = {ua.x, ua.y, ua.z, ua.w, ub.x, ub.y, ub.z, ub.w};
#pragma unroll
            for (int i = 0; i < 8; ++i)
#pragma unroll
                for (int j = 0; j < 8; ++j)
                    acc[i][j] += ss[i] * uu[j];
        }
    }

    // ---- epilogue: stage P and Q through LDS, combine, write partials ----
    __syncthreads();
    {
        float* obuf = smem + (isP ? 0 : 8192);   // [64][128]
#pragma unroll
        for (int i = 0; i < 8; ++i) {
#pragma unroll
            for (int jv = 0; jv < 2; ++jv) {
                float4 w_;
                w_.x = acc[i][4 * jv + 0];
                w_.y = acc[i][4 * jv + 1];
                w_.z = acc[i][4 * jv + 2];
                w_.w = acc[i][4 * jv + 3];
                *(float4*)&obuf[(r0 + i) * 128 + c0 + 4 * jv] = w_;
            }
        }
    }
    __syncthreads();

    const int obase = half * ND_;
#pragma unroll
    for (int e = 0; e < 8; ++e) {
        int idx = e * 256 + t;
        int r   = idx >> 5;                  // 0..63
        int c4  = (idx & 31) << 2;           // 0..124
        float4 P = *(const float4*)&smem[r * 128 + c4];
        float4 Q = *(const float4*)&smem[8192 + r * 128 + c4];
        float4 hv, dv;
        hv.x = 0.5f * (P.x + Q.x); hv.y = 0.5f * (P.y + Q.y);
        hv.z = 0.5f * (P.z + Q.z); hv.w = 0.5f * (P.w + Q.w);
        dv.x = 0.5f * (P.x - Q.x); dv.y = 0.5f * (P.y - Q.y);
        dv.z = 0.5f * (P.z - Q.z); dv.w = 0.5f * (P.w - Q.w);
        if (half == 0) {
            // diag and u = head+dep row slice, read directly from global
            float dgv = alpha[(I0 + r) * NN + (I0 + r)];
            int go = (I0 + r) * DD + C0 + c4;
            float4 hh = *(const float4*)&head[go];
            float4 dd = *(const float4*)&dep[go];
            float4 uu;
            uu.x = hh.x + dd.x; uu.y = hh.y + dd.y;
            uu.z = hh.z + dd.z; uu.w = hh.w + dd.w;
            hv.x -= dgv * uu.x; hv.y -= dgv * uu.y;
            hv.z -= dgv * uu.z; hv.w -= dgv * uu.w;
            dv.x -= dgv * uu.x; dv.y -= dgv * uu.y;
            dv.z -= dgv * uu.z; dv.w -= dgv * uu.w;
        }
        int off = (I0 + r) * DD + C0 + c4;
        *(float4*)&hA[obase + off] = hv;
        *(float4*)&dA[obase + off] = dv;
    }
}

// ---------------------------------------------------------------------------
// stageB<SPLITK>: out = leaky_relu( (sum of SPLITK partials) @ W1 + Y @ W2 )
// Block tile 64 x 128, 256 threads, 4x8 accum/thread, K=256 in BK=32 chunks.
// Grid 512: sel = b>>8 (0 = head output, 1 = dependent output).
// ---------------------------------------------------------------------------
template <int SPLITK>
__global__ __launch_bounds__(256, 2)
void stageB_kernel(const float* __restrict__ hA, const float* __restrict__ dA,
                   const float* __restrict__ head, const float* __restrict__ dep,
                   const float* __restrict__ Wah, const float* __restrict__ Wad,
                   const float* __restrict__ Wch, const float* __restrict__ Wcd,
                   float* __restrict__ out) {
    __shared__ float smem2[12544];
    float* s_x  = smem2;            // [32][68] transposed X tile
    float* s_y  = smem2 + 2176;     // [32][68]
    float* s_w1 = smem2 + 4352;     // [32][128]
    float* s_w2 = smem2 + 8448;     // [32][128] -> 12544

    int b   = blockIdx.x;
    int sel = b >> 8;
    int rem = b & 255;
    int rb  = rem >> 1;
    int cb  = rem & 1;
    int I0  = rb * 64;
    int C0  = cb * 128;

    const float* X  = sel ? dA : hA;        // SPLITK split-K halves, summed on load
    const float* Y  = sel ? dep : head;
    const float* W1 = sel ? Wad : Wah;
    const float* W2 = sel ? Wcd : Wch;
    float* dst = out + sel * ND_;

    int t  = threadIdx.x;
    int rg = t & 15, cg = t >> 4;
    int r0 = rg * 4, c0 = cg * 8;

    float acc[4][8];
#pragma unroll
    for (int i = 0; i < 4; ++i)
#pragma unroll
        for (int j = 0; j < 8; ++j) acc[i][j] = 0.0f;

    for (int it = 0; it < 8; ++it) {
        int k0 = it * 32;
        __syncthreads();
#pragma unroll
        for (int e = 0; e < 2; ++e) {
            int idx = e * 256 + t;
            int r   = idx >> 3;              // 0..63
            int k4  = (idx & 7) << 2;        // 0..28
            int go  = (I0 + r) * DD + k0 + k4;
            float4 xv = *(const float4*)&X[go];
            if (SPLITK == 2) {
                float4 xv2 = *(const float4*)&X[ND_ + go];
                xv.x += xv2.x; xv.y += xv2.y; xv.z += xv2.z; xv.w += xv2.w;
            }
            s_x[(k4 + 0) * 68 + r] = xv.x;
            s_x[(k4 + 1) * 68 + r] = xv.y;
            s_x[(k4 + 2) * 68 + r] = xv.z;
            s_x[(k4 + 3) * 68 + r] = xv.w;
            float4 yv = *(const float4*)&Y[go];
            s_y[(k4 + 0) * 68 + r] = yv.x;
            s_y[(k4 + 1) * 68 + r] = yv.y;
            s_y[(k4 + 2) * 68 + r] = yv.z;
            s_y[(k4 + 3) * 68 + r] = yv.w;
        }
#pragma unroll
        for (int e = 0; e < 4; ++e) {
            int idx = e * 256 + t;
            int kk  = idx >> 5;
            int c4  = (idx & 31) << 2;
            *(float4*)&s_w1[kk * 128 + c4] =
                *(const float4*)&W1[(k0 + kk) * DD + C0 + c4];
            *(float4*)&s_w2[kk * 128 + c4] =
                *(const float4*)&W2[(k0 + kk) * DD + C0 + c4];
        }
        __syncthreads();
#pragma unroll 8
        for (int k = 0; k < 32; ++k) {
            float4 xv = *(const float4*)&s_x[k * 68 + r0];
            float4 yv = *(const float4*)&s_y[k * 68 + r0];
            float4 wa = *(const float4*)&s_w1[k * 128 + c0];
            float4 wb = *(const float4*)&s_w1[k * 128 + c0 + 4];
            float4 wc = *(const float4*)&s_w2[k * 128 + c0];
            float4 wd = *(const float4*)&s_w2[k * 128 + c0 + 4];
            float xs[4]  = {xv.x, xv.y, xv.z, xv.w};
            float ys[4]  = {yv.x, yv.y, yv.z, yv.w};
            float w1s[8] = {wa.x, wa.y, wa.z, wa.w, wb.x, wb.y, wb.z, wb.w};
            float w2s[8] = {wc.x, wc.y, wc.z, wc.w, wd.x, wd.y, wd.z, wd.w};
#pragma unroll
            for (int i = 0; i < 4; ++i)
#pragma unroll
                for (int j = 0; j < 8; ++j)
                    acc[i][j] += xs[i] * w1s[j] + ys[i] * w2s[j];
        }
    }

    // leaky relu + store
#pragma unroll
    for (int i = 0; i < 4; ++i) {
#pragma unroll
        for (int jv = 0; jv < 2; ++jv) {
            float4 o;
            float v0 = acc[i][4 * jv + 0];
            float v1 = acc[i][4 * jv + 1];
            float v2 = acc[i][4 * jv + 2];
            float v3 = acc[i][4 * jv + 3];
            o.x = v0 >= 0.0f ? v0 : NEG_SLOPE * v0;
            o.y = v1 >= 0.0f ? v1 : NEG_SLOPE * v1;
            o.z = v2 >= 0.0f ? v2 : NEG_SLOPE * v2;
            o.w = v3 >= 0.0f ? v3 : NEG_SLOPE * v3;
            *(float4*)&dst[(I0 + r0 + i) * DD + C0 + c0 + 4 * jv] = o;
        }
    }
}

// ---------------------------------------------------------------------------
// kernel_launch
// workspace layout (floats): hA[SPLITK*ND] dA[SPLITK*ND]
//   SPLITK=2 -> 33.6 MB;  SPLITK=1 fallback -> 16.8 MB.
//   SPLITK chosen from ws_size (constant across calls -> deterministic).
// ---------------------------------------------------------------------------
extern "C" void kernel_launch(void* const* d_in, const int* in_sizes, int n_in,
                              void* d_out, int out_size, void* d_ws, size_t ws_size,
                              hipStream_t stream) {
    const float* head  = (const float*)d_in[0];
    const float* dep   = (const float*)d_in[1];
    const float* alpha = (const float*)d_in[2];
    const float* Wah   = (const float*)d_in[3];
    const float* Wad   = (const float*)d_in[4];
    const float* Wch   = (const float*)d_in[5];
    const float* Wcd   = (const float*)d_in[6];
    float* out = (float*)d_out;

    float* ws = (float*)d_ws;

    const size_t need2 = (size_t)4 * ND_ * sizeof(float);  // 33.6 MB
    if (ws_size >= need2) {
        float* hA = ws;                 // 2*ND
        float* dA = hA + 2 * ND_;       // 2*ND
        agg_kernel<2><<<512, 256, 0, stream>>>(alpha, head, dep, hA, dA);
        stageB_kernel<2><<<512, 256, 0, stream>>>(hA, dA, head, dep,
                                                  Wah, Wad, Wch, Wcd, out);
    } else {
        float* hA = ws;                 // ND
        float* dA = hA + ND_;           // ND
        agg_kernel<1><<<256, 256, 0, stream>>>(alpha, head, dep, hA, dA);
        stageB_kernel<1><<<512, 256, 0, stream>>>(hA, dA, head, dep,
                                                  Wah, Wad, Wch, Wcd, out);
    }
}

// Round 4
// 517.007 us; speedup vs baseline: 1.8044x; 1.8044x over previous
//
#include <hip/hip_runtime.h>

// Problem constants (N=8192 rows, D=256 features)
#define NN 8192
#define DD 256
#define ND_ (NN * DD)

#define NEG_SLOPE 0.1f

typedef _Float16 half8 __attribute__((ext_vector_type(8)));
typedef _Float16 half4 __attribute__((ext_vector_type(4)));
typedef float f32x4 __attribute__((ext_vector_type(4)));

// ---------------------------------------------------------------------------
// prep_split: build transposed f16 hi/lo splits of u = h+d and v = h-d:
//   uT_hi/uT_lo/vT_hi/vT_lo : [DD=256 feature][NN=8192 node] f16
// Tile 64 node x 64 feature via LDS transpose. Grid 128*4 = 512 blocks.
// ---------------------------------------------------------------------------
__global__ __launch_bounds__(256, 2)
void prep_split_kernel(const float* __restrict__ h, const float* __restrict__ d,
                       _Float16* __restrict__ uT_hi, _Float16* __restrict__ uT_lo,
                       _Float16* __restrict__ vT_hi, _Float16* __restrict__ vT_lo) {
    __shared__ float s_h[64 * 68];
    __shared__ float s_d[64 * 68];
    const int b  = blockIdx.x;
    const int kt = b >> 2;          // node-tile 0..127
    const int ct = b & 3;           // feature-tile 0..3
    const int k0 = kt * 64;
    const int c0 = ct * 64;
    const int t  = threadIdx.x;

#pragma unroll
    for (int e = 0; e < 4; ++e) {
        int idx = e * 256 + t;
        int r   = idx >> 4;                  // node 0..63
        int c4  = (idx & 15) << 2;           // feature 0..60
        float4 hv = *(const float4*)&h[(size_t)(k0 + r) * DD + c0 + c4];
        float4 dv = *(const float4*)&d[(size_t)(k0 + r) * DD + c0 + c4];
        *(float4*)&s_h[r * 68 + c4] = hv;
        *(float4*)&s_d[r * 68 + c4] = dv;
    }
    __syncthreads();

#pragma unroll
    for (int e = 0; e < 2; ++e) {
        int idx = e * 256 + t;
        int c   = idx >> 3;                  // feature-in-tile 0..63
        int seg = idx & 7;                   // node chunk of 8
        half8 uh, ul, vh, vl;
#pragma unroll
        for (int m = 0; m < 8; ++m) {
            float hh = s_h[(seg * 8 + m) * 68 + c];
            float dd = s_d[(seg * 8 + m) * 68 + c];
            float uu = hh + dd;
            float vv = hh - dd;
            _Float16 a = (_Float16)uu;
            uh[m] = a;
            ul[m] = (_Float16)(uu - (float)a);
            _Float16 bb = (_Float16)vv;
            vh[m] = bb;
            vl[m] = (_Float16)(vv - (float)bb);
        }
        size_t go = (size_t)(c0 + c) * NN + k0 + seg * 8;
        *(half8*)&uT_hi[go] = uh;
        *(half8*)&uT_lo[go] = ul;
        *(half8*)&vT_hi[go] = vh;
        *(half8*)&vT_lo[go] = vl;
    }
}

// ---------------------------------------------------------------------------
// agg_mfma: fp32-emulated-via-f16x3 MFMA computation of split-K partials:
//   P = (A + A^T) @ u      Q = (A^T - A) @ v
// stored as f16 in Pbuf/Qbuf [2 halves][NN][DD].
//
// Block: 64 rows x 256 cols, 512 threads (8 waves).
//   waves 0-3: P (cols w*64..w*64+63);  waves 4-7: Q.
//   Per wave: 64x64 tile = 4x4 frags of 16x16, f16x3 -> 48 MFMA / K-step.
// Grid: 256 blocks = 128 row-blocks x 2 K-halves.
// ---------------------------------------------------------------------------
__global__ __launch_bounds__(512, 2)
void agg_mfma_kernel(const float* __restrict__ alpha,
                     const _Float16* __restrict__ uT_hi, const _Float16* __restrict__ uT_lo,
                     const _Float16* __restrict__ vT_hi, const _Float16* __restrict__ vT_lo,
                     _Float16* __restrict__ Pbuf,   // [2][NN][DD]
                     _Float16* __restrict__ Qbuf) { // [2][NN][DD]
    // LDS carve (all chunks 16B-aligned):
    //  s_a1  : float [64][33]      raw A row-slab (for transpose)     8448 B
    //  sS_hi/sS_lo/sD_hi/sD_lo : f16 [64 r][40 k-pitch]               4*5120 B
    //  sB[4] : f16 [256 c][40 k-pitch]  (uT_hi,uT_lo,vT_hi,vT_lo)     4*20480 B
    __shared__ unsigned char smem[110848];
    float*    s_a1  = (float*)smem;                           // 8448 B
    _Float16* sS_hi = (_Float16*)(smem + 8448);
    _Float16* sS_lo = (_Float16*)(smem + 8448 + 5120);
    _Float16* sD_hi = (_Float16*)(smem + 8448 + 10240);
    _Float16* sD_lo = (_Float16*)(smem + 8448 + 15360);
    _Float16* sB0   = (_Float16*)(smem + 28928);              // uT_hi tile
    _Float16* sB1   = (_Float16*)(smem + 28928 + 20480);      // uT_lo
    _Float16* sB2   = (_Float16*)(smem + 28928 + 40960);      // vT_hi
    _Float16* sB3   = (_Float16*)(smem + 28928 + 61440);      // vT_lo

    const int b    = blockIdx.x;
    const int half = b & 1;
    const int rb   = b >> 1;
    const int I0   = rb * 64;
    const int t    = threadIdx.x;
    const int w    = t >> 6;
    const int lane = t & 63;

    const bool isP = (w < 4);
    const int  cw  = w & 3;                // 64-col band within 256

    const _Float16* aHi = isP ? sS_hi : sD_hi;
    const _Float16* aLo = isP ? sS_lo : sD_lo;
    const _Float16* bHi = isP ? sB0 : sB2;
    const _Float16* bLo = isP ? sB1 : sB3;

    const _Float16* gB[4] = {uT_hi, uT_lo, vT_hi, vT_lo};
    _Float16* sBp[4] = {sB0, sB1, sB2, sB3};

    f32x4 acc[4][4];
#pragma unroll
    for (int i = 0; i < 4; ++i)
#pragma unroll
        for (int j = 0; j < 4; ++j) acc[i][j] = (f32x4){0.f, 0.f, 0.f, 0.f};

    // staging index precompute
    const int r_a1 = t >> 3;               // 0..63
    const int k4a  = (t & 7) << 2;         // 0..28
    const int kk   = t >> 4;               // 0..31
    const int r4   = (t & 15) << 2;        // 0..60
    const int lrow = lane & 15;
    const int lk   = (lane >> 4) * 8;

    const int kbase = half * (NN / 2);

    for (int it = 0; it < 128; ++it) {
        const int k0g = kbase + it * 32;
        __syncthreads();   // previous iteration's LDS reads complete

        // ---- stage: alpha row-slab -> s_a1 ----
        float4 av = *(const float4*)&alpha[(size_t)(I0 + r_a1) * NN + k0g + k4a];
        // ---- stage: alpha col-slab -> regs ----
        float4 a2 = *(const float4*)&alpha[(size_t)(k0g + kk) * NN + I0 + r4];
        // ---- stage: B tiles (uT/vT hi/lo) -> sB ----
#pragma unroll
        for (int arr = 0; arr < 4; ++arr) {
#pragma unroll
            for (int rep = 0; rep < 2; ++rep) {
                int idx = rep * 512 + t;
                int c   = idx >> 2;            // 0..255
                int seg = idx & 3;             // k chunk of 8
                float4 bv = *(const float4*)&gB[arr][(size_t)c * NN + k0g + seg * 8];
                *(float4*)&sBp[arr][c * 40 + seg * 8] = bv;
            }
        }
        s_a1[r_a1 * 33 + k4a + 0] = av.x;
        s_a1[r_a1 * 33 + k4a + 1] = av.y;
        s_a1[r_a1 * 33 + k4a + 2] = av.z;
        s_a1[r_a1 * 33 + k4a + 3] = av.w;
        __syncthreads();   // s_a1 ready

        // ---- build S = A^T+A, D = A^T-A tiles in f16 hi/lo, layout [r][k] ----
        float tr0 = s_a1[(r4 + 0) * 33 + kk];
        float tr1 = s_a1[(r4 + 1) * 33 + kk];
        float tr2 = s_a1[(r4 + 2) * 33 + kk];
        float tr3 = s_a1[(r4 + 3) * 33 + kk];
        float sv[4], dv[4];
        sv[0] = a2.x + tr0; dv[0] = a2.x - tr0;
        sv[1] = a2.y + tr1; dv[1] = a2.y - tr1;
        sv[2] = a2.z + tr2; dv[2] = a2.z - tr2;
        sv[3] = a2.w + tr3; dv[3] = a2.w - tr3;
#pragma unroll
        for (int j = 0; j < 4; ++j) {
            int adr = (r4 + j) * 40 + kk;
            _Float16 sh = (_Float16)sv[j];
            sS_hi[adr] = sh;
            sS_lo[adr] = (_Float16)(sv[j] - (float)sh);
            _Float16 dh = (_Float16)dv[j];
            sD_hi[adr] = dh;
            sD_lo[adr] = (_Float16)(dv[j] - (float)dh);
        }
        __syncthreads();   // S/D/B tiles ready

        // ---- inner: 48 MFMA per wave ----
        half8 aH[4], aL[4];
#pragma unroll
        for (int rf = 0; rf < 4; ++rf) {
            aH[rf] = *(const half8*)&aHi[(rf * 16 + lrow) * 40 + lk];
            aL[rf] = *(const half8*)&aLo[(rf * 16 + lrow) * 40 + lk];
        }
#pragma unroll
        for (int cf = 0; cf < 4; ++cf) {
            int cc = (cw * 64 + cf * 16 + lrow) * 40 + lk;
            half8 bH = *(const half8*)&bHi[cc];
            half8 bL = *(const half8*)&bLo[cc];
#pragma unroll
            for (int rf = 0; rf < 4; ++rf) {
                acc[rf][cf] = __builtin_amdgcn_mfma_f32_16x16x32_f16(aH[rf], bH, acc[rf][cf], 0, 0, 0);
                acc[rf][cf] = __builtin_amdgcn_mfma_f32_16x16x32_f16(aH[rf], bL, acc[rf][cf], 0, 0, 0);
                acc[rf][cf] = __builtin_amdgcn_mfma_f32_16x16x32_f16(aL[rf], bH, acc[rf][cf], 0, 0, 0);
            }
        }
    }

    // ---- epilogue: write f16 partials ----
    _Float16* dst = (isP ? Pbuf : Qbuf) + (size_t)half * ND_;
#pragma unroll
    for (int rf = 0; rf < 4; ++rf) {
#pragma unroll
        for (int cf = 0; cf < 4; ++cf) {
#pragma unroll
            for (int reg = 0; reg < 4; ++reg) {
                int row = I0 + rf * 16 + (lane >> 4) * 4 + reg;
                int col = cw * 64 + cf * 16 + (lane & 15);
                dst[(size_t)row * DD + col] = (_Float16)acc[rf][cf][reg];
            }
        }
    }
}

// ---------------------------------------------------------------------------
// stageB: combine P/Q partials into agg, then
//   out = leaky_relu( agg @ W1 + Y @ W2 )
// Block tile 64 x 128, 256 threads, 4x8 accum/thread, K=256 in BK=32 chunks.
// Grid 512: sel = b>>8 (0 = head output, 1 = dependent output).
// ---------------------------------------------------------------------------
__global__ __launch_bounds__(256, 2)
void stageB_kernel(const _Float16* __restrict__ Pbuf, const _Float16* __restrict__ Qbuf,
                   const float* __restrict__ head, const float* __restrict__ dep,
                   const float* __restrict__ alpha,
                   const float* __restrict__ Wah, const float* __restrict__ Wad,
                   const float* __restrict__ Wch, const float* __restrict__ Wcd,
                   float* __restrict__ out) {
    __shared__ float smem2[12544];
    __shared__ float s_dg[64];
    float* s_x  = smem2;            // [32][68] transposed X tile
    float* s_y  = smem2 + 2176;     // [32][68]
    float* s_w1 = smem2 + 4352;     // [32][128]
    float* s_w2 = smem2 + 8448;     // [32][128] -> 12544

    int b   = blockIdx.x;
    int sel = b >> 8;
    int rem = b & 255;
    int rb  = rem >> 1;
    int cb  = rem & 1;
    int I0  = rb * 64;
    int C0  = cb * 128;

    const float* Y  = sel ? dep : head;
    const float* W1 = sel ? Wad : Wah;
    const float* W2 = sel ? Wcd : Wch;
    float* dst = out + sel * ND_;

    int t  = threadIdx.x;
    int rg = t & 15, cg = t >> 4;
    int r0 = rg * 4, c0 = cg * 8;

    if (t < 64) s_dg[t] = alpha[(size_t)(I0 + t) * NN + I0 + t];

    float acc[4][8];
#pragma unroll
    for (int i = 0; i < 4; ++i)
#pragma unroll
        for (int j = 0; j < 8; ++j) acc[i][j] = 0.0f;

    for (int it = 0; it < 8; ++it) {
        int k0 = it * 32;
        __syncthreads();
#pragma unroll
        for (int e = 0; e < 2; ++e) {
            int idx = e * 256 + t;
            int r   = idx >> 3;              // 0..63
            int k4  = (idx & 7) << 2;        // 0..28
            size_t go = (size_t)(I0 + r) * DD + k0 + k4;
            half4 p0 = *(const half4*)&Pbuf[go];
            half4 p1 = *(const half4*)&Pbuf[ND_ + go];
            half4 q0 = *(const half4*)&Qbuf[go];
            half4 q1 = *(const half4*)&Qbuf[ND_ + go];
            float4 hv = *(const float4*)&head[go];
            float4 dv = *(const float4*)&dep[go];
            float dgv = s_dg[r];
            float hj[4] = {hv.x, hv.y, hv.z, hv.w};
            float dj[4] = {dv.x, dv.y, dv.z, dv.w};
#pragma unroll
            for (int j = 0; j < 4; ++j) {
                float Pv = (float)p0[j] + (float)p1[j];
                float Qv = (float)q0[j] + (float)q1[j];
                float uu = hj[j] + dj[j];
                float x  = (sel ? 0.5f * (Pv - Qv) : 0.5f * (Pv + Qv)) - dgv * uu;
                s_x[(k4 + j) * 68 + r] = x;
                s_y[(k4 + j) * 68 + r] = sel ? dj[j] : hj[j];
            }
        }
#pragma unroll
        for (int e = 0; e < 4; ++e) {
            int idx = e * 256 + t;
            int kkk = idx >> 5;
            int c4  = (idx & 31) << 2;
            *(float4*)&s_w1[kkk * 128 + c4] =
                *(const float4*)&W1[(size_t)(k0 + kkk) * DD + C0 + c4];
            *(float4*)&s_w2[kkk * 128 + c4] =
                *(const float4*)&W2[(size_t)(k0 + kkk) * DD + C0 + c4];
        }
        __syncthreads();
#pragma unroll 8
        for (int k = 0; k < 32; ++k) {
            float4 xv = *(const float4*)&s_x[k * 68 + r0];
            float4 yv = *(const float4*)&s_y[k * 68 + r0];
            float4 wa = *(const float4*)&s_w1[k * 128 + c0];
            float4 wb = *(const float4*)&s_w1[k * 128 + c0 + 4];
            float4 wc = *(const float4*)&s_w2[k * 128 + c0];
            float4 wd = *(const float4*)&s_w2[k * 128 + c0 + 4];
            float xs[4]  = {xv.x, xv.y, xv.z, xv.w};
            float ys[4]  = {yv.x, yv.y, yv.z, yv.w};
            float w1s[8] = {wa.x, wa.y, wa.z, wa.w, wb.x, wb.y, wb.z, wb.w};
            float w2s[8] = {wc.x, wc.y, wc.z, wc.w, wd.x, wd.y, wd.z, wd.w};
#pragma unroll
            for (int i = 0; i < 4; ++i)
#pragma unroll
                for (int j = 0; j < 8; ++j)
                    acc[i][j] += xs[i] * w1s[j] + ys[i] * w2s[j];
        }
    }

    // leaky relu + store
#pragma unroll
    for (int i = 0; i < 4; ++i) {
#pragma unroll
        for (int jv = 0; jv < 2; ++jv) {
            float4 o;
            float v0 = acc[i][4 * jv + 0];
            float v1 = acc[i][4 * jv + 1];
            float v2 = acc[i][4 * jv + 2];
            float v3 = acc[i][4 * jv + 3];
            o.x = v0 >= 0.0f ? v0 : NEG_SLOPE * v0;
            o.y = v1 >= 0.0f ? v1 : NEG_SLOPE * v1;
            o.z = v2 >= 0.0f ? v2 : NEG_SLOPE * v2;
            o.w = v3 >= 0.0f ? v3 : NEG_SLOPE * v3;
            *(float4*)&dst[(size_t)(I0 + r0 + i) * DD + C0 + c0 + 4 * jv] = o;
        }
    }
}

// ---------------------------------------------------------------------------
// kernel_launch
// workspace layout (_Float16 units):
//   uT_hi[ND] uT_lo[ND] vT_hi[ND] vT_lo[ND] P[2*ND] Q[2*ND]
//   total = 8*ND f16 = 32 MB (same footprint as the previously-passing run)
// ---------------------------------------------------------------------------
extern "C" void kernel_launch(void* const* d_in, const int* in_sizes, int n_in,
                              void* d_out, int out_size, void* d_ws, size_t ws_size,
                              hipStream_t stream) {
    const float* head  = (const float*)d_in[0];
    const float* dep   = (const float*)d_in[1];
    const float* alpha = (const float*)d_in[2];
    const float* Wah   = (const float*)d_in[3];
    const float* Wad   = (const float*)d_in[4];
    const float* Wch   = (const float*)d_in[5];
    const float* Wcd   = (const float*)d_in[6];
    float* out = (float*)d_out;

    _Float16* ws   = (_Float16*)d_ws;
    _Float16* uT_hi = ws;
    _Float16* uT_lo = ws + (size_t)ND_;
    _Float16* vT_hi = ws + (size_t)2 * ND_;
    _Float16* vT_lo = ws + (size_t)3 * ND_;
    _Float16* Pbuf  = ws + (size_t)4 * ND_;   // [2][NN][DD]
    _Float16* Qbuf  = ws + (size_t)6 * ND_;   // [2][NN][DD]

    prep_split_kernel<<<512, 256, 0, stream>>>(head, dep, uT_hi, uT_lo, vT_hi, vT_lo);
    agg_mfma_kernel<<<256, 512, 0, stream>>>(alpha, uT_hi, uT_lo, vT_hi, vT_lo, Pbuf, Qbuf);
    stageB_kernel<<<512, 256, 0, stream>>>(Pbuf, Qbuf, head, dep, alpha,
                                           Wah, Wad, Wch, Wcd, out);
}